// Round 1
// baseline (2852.787 us; speedup 1.0000x reference)
//
#include <hip/hip_runtime.h>
#include <cstddef>

// DeformLayer: offset conv3x3 (27ch) -> split dy/dx/mask(sigmoid) -> deform conv
// (bilinear gather * mask, einsum with w_dcn) -> BN1+ReLU -> y (output 0)
// -> 4x4 stride-2 transposed conv -> BN2+ReLU -> up (output 1)
// Shapes: B=8, C=O=256, H=W=64; up is 128x128.
// All fp32 this round (correctness baseline). GEMM-tiled, LDS-staged.

#define B_EPS 1e-5f

__device__ __forceinline__ void fma4(float (&a)[4], float wv, const float4& v) {
    a[0] = fmaf(wv, v.x, a[0]);
    a[1] = fmaf(wv, v.y, a[1]);
    a[2] = fmaf(wv, v.z, a[2]);
    a[3] = fmaf(wv, v.w, a[3]);
}

// ---------------- weight transposes (tiny) ----------------
// w_off[27][256][9] -> wofft[c][co*9+t]   (uniform scalar loads in offset conv)
__global__ __launch_bounds__(256) void k_tr_woff(const float* __restrict__ w,
                                                 float* __restrict__ o) {
    int i = blockIdx.x * 256 + threadIdx.x;      // 62208 = 243*256
    int t9 = i % 9; int r = i / 9; int c = r & 255; int co = r >> 8;
    o[c * 243 + co * 9 + t9] = w[i];
}

// w_dcn[o][c][9] -> Wd[(k*256+c)*256 + o]  (coalesced o staging in deform GEMM)
__global__ __launch_bounds__(256) void k_tr_wdcn(const float* __restrict__ w,
                                                 float* __restrict__ o) {
    int i = blockIdx.x * 256 + threadIdx.x;      // 589824
    int t9 = i % 9; int r = i / 9; int c = r & 255; int oc = r >> 8;
    o[(t9 * 256 + c) * 256 + oc] = w[i];
}

// w_up[ci][co][wr][wc] -> Wt[(wr*4+wc)*65536 + ci*256 + co]
__global__ __launch_bounds__(256) void k_tr_wup(const float* __restrict__ w,
                                                float* __restrict__ o) {
    int i = blockIdx.x * 256 + threadIdx.x;      // 1048576
    int wrc = i & 15; int co = (i >> 4) & 255; int ci = i >> 12;
    o[wrc * 65536 + ci * 256 + co] = w[i];
}

// ---------------- offset conv: om[b][27][64][64] ----------------
// block = (b, 4-row group); thread = one pixel, all 27 output channels.
// x loads amortized 27x; weights uniform per block -> scalar loads.
__global__ __launch_bounds__(256) void k_offset_conv(
    const float* __restrict__ x, const float* __restrict__ wofft,
    const float* __restrict__ b_off, float* __restrict__ om)
{
    const int t = threadIdx.x;
    const int b = blockIdx.x >> 4;
    const int h = ((blockIdx.x & 15) << 2) + (t >> 6);
    const int w = t & 63;
    const float* xb = x + ((size_t)b << 20);     // b*256*4096
    float acc[27];
#pragma unroll
    for (int i = 0; i < 27; ++i) acc[i] = b_off[i];
    for (int c = 0; c < 256; ++c) {
        const float* xc = xb + (c << 12);
        float xv[9];
#pragma unroll
        for (int tr = 0; tr < 3; ++tr) {
            int hh = h + tr - 1;
            bool vy = (unsigned)hh < 64u;
#pragma unroll
            for (int tc = 0; tc < 3; ++tc) {
                int ww = w + tc - 1;
                xv[tr * 3 + tc] = (vy && (unsigned)ww < 64u) ? xc[(hh << 6) + ww] : 0.f;
            }
        }
        const float* wc = wofft + c * 243;
#pragma unroll
        for (int co = 0; co < 27; ++co)
#pragma unroll
            for (int k = 0; k < 9; ++k)
                acc[co] = fmaf(xv[k], wc[co * 9 + k], acc[co]);
    }
    float* omb = om + (size_t)b * 110592 + (h << 6) + w;  // 27*4096
#pragma unroll
    for (int co = 0; co < 27; ++co) {
        float a = acc[co];
        if (co >= 18) a = 1.f / (1.f + __expf(-a));       // sigmoid(mask)
        omb[co << 12] = a;
    }
}

// ---------------- bilinear coeff prep ----------------
// per (b,k,pix): 4 clipped corner indices + 4 weights (validity & mask folded in).
// Note reference quirk: dy = offset[:, :9] = ox-channels(0..8), dx = channels 9..17.
__global__ __launch_bounds__(256) void k_prep_coeff(
    const float* __restrict__ om, int4* __restrict__ cidx, float4* __restrict__ cwgt)
{
    int i = blockIdx.x * 256 + threadIdx.x;      // 294912 = 8*9*4096
    int pix = i & 4095;
    int bk = i >> 12;
    int k = bk % 9;
    int b = bk / 9;
    int h = pix >> 6, w = pix & 63;
    const float* omb = om + (size_t)b * 110592;
    float dy = omb[(k << 12) + pix];
    float dx = omb[((9 + k) << 12) + pix];
    float m  = omb[((18 + k) << 12) + pix];      // already sigmoided
    float py = dy + (float)(k / 3 - 1 + h);
    float px = dx + (float)(k % 3 - 1 + w);
    float y0f = floorf(py), x0f = floorf(px);
    float wy = py - y0f, wx = px - x0f;
    int y0 = (int)y0f, x0 = (int)x0f;
    int y1 = y0 + 1, x1 = x0 + 1;
    float vy0 = ((unsigned)y0 < 64u) ? 1.f : 0.f;
    float vy1 = ((unsigned)y1 < 64u) ? 1.f : 0.f;
    float vx0 = ((unsigned)x0 < 64u) ? 1.f : 0.f;
    float vx1 = ((unsigned)x1 < 64u) ? 1.f : 0.f;
    int cy0 = min(max(y0, 0), 63), cy1 = min(max(y1, 0), 63);
    int cx0 = min(max(x0, 0), 63), cx1 = min(max(x1, 0), 63);
    cidx[i] = make_int4((cy0 << 6) + cx0, (cy0 << 6) + cx1,
                        (cy1 << 6) + cx0, (cy1 << 6) + cx1);
    cwgt[i] = make_float4(m * (1.f - wy) * (1.f - wx) * vy0 * vx0,
                          m * (1.f - wy) * wx         * vy0 * vx1,
                          m * wy         * (1.f - wx) * vy1 * vx0,
                          m * wy         * wx         * vy1 * vx1);
}

// ---------------- deform conv GEMM + BN1 + ReLU -> y ----------------
// per block: batch b, 64 o-channels, one image row h (64 pixels).
// K = 9(k, outer) * 256(c, inner) = 2304, chunked by 16.
__global__ __launch_bounds__(256) void k_deform_gemm(
    const float* __restrict__ x, const float* __restrict__ Wd,
    const int4* __restrict__ cidx, const float4* __restrict__ cwgt,
    const float* __restrict__ g1, const float* __restrict__ be1,
    const float* __restrict__ mu1, const float* __restrict__ va1,
    float* __restrict__ yout)
{
    __shared__ int4   sIdx[9][64];
    __shared__ float4 sWgt[9][64];
    __shared__ float  sVal[16][68];
    __shared__ float  sW[16][68];

    const int t = threadIdx.x;
    const int blk = blockIdx.x;          // b*256 + ot*64 + h
    const int h   = blk & 63;
    const int ot  = (blk >> 6) & 3;
    const int b   = blk >> 8;
    const int pix0 = h << 6;
    const int o0 = ot << 6;

    for (int e = t; e < 576; e += 256) {
        int k = e >> 6, pl = e & 63;
        int gi = (b * 9 + k) * 4096 + pix0 + pl;
        sIdx[k][pl] = cidx[gi];
        sWgt[k][pl] = cwgt[gi];
    }
    __syncthreads();

    float acc[4][4];
#pragma unroll
    for (int i = 0; i < 4; ++i)
#pragma unroll
        for (int j = 0; j < 4; ++j) acc[i][j] = 0.f;

    const int pl  = t & 63;      // staging pixel (fixed per thread)
    const int ci0 = t >> 6;      // 0..3
    const int ol  = t & 63;      // w staging o
    const int olg = (t & 15) << 2;
    const int plg = (t >> 4) << 2;
    const float* xb = x + ((size_t)b << 20);

    for (int kc = 0; kc < 144; ++kc) {
        const int k  = kc >> 4;            // 0..8 (uniform per chunk)
        const int c0 = (kc & 15) << 4;     // 0..240
        int4   id4 = sIdx[k][pl];
        float4 wg4 = sWgt[k][pl];
        float vals[4], ws4[4];
#pragma unroll
        for (int j = 0; j < 4; ++j) {
            int c = c0 + ci0 + (j << 2);
            const float* xc = xb + (c << 12);
            vals[j] = wg4.x * xc[id4.x] + wg4.y * xc[id4.y]
                    + wg4.z * xc[id4.z] + wg4.w * xc[id4.w];
            ws4[j] = Wd[((k << 8) + c) * 256 + o0 + ol];
        }
        __syncthreads();
#pragma unroll
        for (int j = 0; j < 4; ++j) {
            sVal[ci0 + (j << 2)][pl] = vals[j];
            sW[ci0 + (j << 2)][ol]   = ws4[j];
        }
        __syncthreads();
#pragma unroll
        for (int kk = 0; kk < 16; ++kk) {
            float4 v4 = *(const float4*)&sVal[kk][plg];
            float4 w4 = *(const float4*)&sW[kk][olg];
            fma4(acc[0], w4.x, v4);
            fma4(acc[1], w4.y, v4);
            fma4(acc[2], w4.z, v4);
            fma4(acc[3], w4.w, v4);
        }
    }
#pragma unroll
    for (int i = 0; i < 4; ++i) {
        int o = o0 + olg + i;
        float sc = g1[o] * rsqrtf(va1[o] + B_EPS);
        float bi = be1[o] - mu1[o] * sc;
        float4 r;
        r.x = fmaxf(fmaf(acc[i][0], sc, bi), 0.f);
        r.y = fmaxf(fmaf(acc[i][1], sc, bi), 0.f);
        r.z = fmaxf(fmaf(acc[i][2], sc, bi), 0.f);
        r.w = fmaxf(fmaf(acc[i][3], sc, bi), 0.f);
        *(float4*)&yout[((size_t)(b * 256 + o) << 12) + pix0 + plg] = r;
    }
}

// ---------------- deconv(4x4, stride2) GEMM + BN2 + ReLU -> up ----------------
// parity class (ca, cb): up[b, co, 2h'+ca, 2w'+cb]. Each class = GEMM:
//   K = 256 ci * 4 taps; tap rows: ca=0:{(dh=-1,wr=3),(0,1)} ca=1:{(0,2),(+1,0)}
// per block: b, class, 128 co, one h' row (64 pixels). M=128,N=64.
__global__ __launch_bounds__(256) void k_deconv_gemm(
    const float* __restrict__ y, const float* __restrict__ Wt,
    const float* __restrict__ g2, const float* __restrict__ be2,
    const float* __restrict__ mu2, const float* __restrict__ va2,
    float* __restrict__ up)
{
    __shared__ float sY[16][68];
    __shared__ float sWk[16][132];

    const int t = threadIdx.x;
    const int blk = blockIdx.x;          // ((b*4+cls)*2+ot)*64 + h0
    const int h0  = blk & 63;
    const int ot  = (blk >> 6) & 1;
    const int cls = (blk >> 7) & 3;
    const int b   = blk >> 9;
    const int ca = cls >> 1, cb = cls & 1;

    const int DH0 = ca ? 0 : -1, DH1 = ca ? 1 : 0;
    const int WR0 = ca ? 2 : 3,  WR1 = ca ? 0 : 1;
    const int DW0 = cb ? 0 : -1, DW1 = cb ? 1 : 0;
    const int WC0 = cb ? 2 : 3,  WC1 = cb ? 0 : 1;

    const int o0 = ot << 7;
    const float* yb = y + ((size_t)b << 20);

    float acc[8][4];
#pragma unroll
    for (int i = 0; i < 8; ++i)
#pragma unroll
        for (int j = 0; j < 4; ++j) acc[i][j] = 0.f;

    const int pls  = t & 63;      // staging pixel w'
    const int kls0 = t >> 6;      // 0..3
    const int olw  = t & 127;
    const int klw0 = t >> 7;      // 0..1
    const int olg = (t & 15) << 3;
    const int plg = (t >> 4) << 2;

    for (int kc = 0; kc < 64; ++kc) {
        const int c0 = kc << 2;   // 4 ci per chunk; kl = ci_l*4 + tap
        float vy[4], vw[8];
#pragma unroll
        for (int j = 0; j < 4; ++j) {
            int kl = kls0 + (j << 2);
            int ci = c0 + (kl >> 2);
            int tap = kl & 3;
            int dh = (tap >> 1) ? DH1 : DH0;
            int dw = (tap & 1) ? DW1 : DW0;
            int hh = h0 + dh;
            int ww = pls + dw;
            bool v = ((unsigned)hh < 64u) && ((unsigned)ww < 64u);
            vy[j] = v ? yb[(ci << 12) + (hh << 6) + ww] : 0.f;
        }
#pragma unroll
        for (int j = 0; j < 8; ++j) {
            int kl = klw0 + (j << 1);
            int ci = c0 + (kl >> 2);
            int tap = kl & 3;
            int wr = (tap >> 1) ? WR1 : WR0;
            int wc = (tap & 1) ? WC1 : WC0;
            vw[j] = Wt[(((wr << 2) + wc) << 16) + (ci << 8) + o0 + olw];
        }
        __syncthreads();
#pragma unroll
        for (int j = 0; j < 4; ++j) sY[kls0 + (j << 2)][pls] = vy[j];
#pragma unroll
        for (int j = 0; j < 8; ++j) sWk[klw0 + (j << 1)][olw] = vw[j];
        __syncthreads();
#pragma unroll
        for (int kk = 0; kk < 16; ++kk) {
            float4 v4 = *(const float4*)&sY[kk][plg];
            float4 wa = *(const float4*)&sWk[kk][olg];
            float4 wb = *(const float4*)&sWk[kk][olg + 4];
            fma4(acc[0], wa.x, v4);
            fma4(acc[1], wa.y, v4);
            fma4(acc[2], wa.z, v4);
            fma4(acc[3], wa.w, v4);
            fma4(acc[4], wb.x, v4);
            fma4(acc[5], wb.y, v4);
            fma4(acc[6], wb.z, v4);
            fma4(acc[7], wb.w, v4);
        }
    }
    float* ub = up + ((size_t)b << 22);          // b*256*16384
    const int p = (h0 << 1) + ca;
#pragma unroll
    for (int i = 0; i < 8; ++i) {
        int o = o0 + olg + i;
        float sc = g2[o] * rsqrtf(va2[o] + B_EPS);
        float bi = be2[o] - mu2[o] * sc;
#pragma unroll
        for (int j = 0; j < 4; ++j) {
            int q = ((plg + j) << 1) + cb;
            ub[(o << 14) + (p << 7) + q] = fmaxf(fmaf(acc[i][j], sc, bi), 0.f);
        }
    }
}

extern "C" void kernel_launch(void* const* d_in, const int* in_sizes, int n_in,
                              void* d_out, int out_size, void* d_ws, size_t ws_size,
                              hipStream_t stream)
{
    const float* x     = (const float*)d_in[0];
    const float* w_off = (const float*)d_in[1];
    const float* b_off = (const float*)d_in[2];
    const float* w_dcn = (const float*)d_in[3];
    const float* g1    = (const float*)d_in[4];
    const float* be1   = (const float*)d_in[5];
    const float* mu1   = (const float*)d_in[6];
    const float* va1   = (const float*)d_in[7];
    const float* w_up  = (const float*)d_in[8];
    const float* g2    = (const float*)d_in[9];
    const float* be2   = (const float*)d_in[10];
    const float* mu2   = (const float*)d_in[11];
    const float* va2   = (const float*)d_in[12];

    float* yout = (float*)d_out;                 // 8*256*64*64 = 8388608
    float* up   = (float*)d_out + 8388608;       // 8*256*128*128

    char* ws = (char*)d_ws;
    float*  om    = (float*)(ws + 0);            // 884736 f  (3538944 B)
    float*  wofft = (float*)(ws + 3538944);      // 62208 f   (248832 B)
    int4*   cidx  = (int4*) (ws + 3787776);      // 294912 i4 (4718592 B)
    float4* cwgt  = (float4*)(ws + 8506368);     // 294912 f4 (4718592 B)
    float*  Wd    = (float*)(ws + 13224960);     // 589824 f  (2359296 B)
    float*  Wt    = (float*)(ws + 15584256);     // 1048576 f (4194304 B)
    // total ws use: 19778560 B (~19.8 MB)

    k_tr_woff   <<<243,  256, 0, stream>>>(w_off, wofft);
    k_tr_wdcn   <<<2304, 256, 0, stream>>>(w_dcn, Wd);
    k_tr_wup    <<<4096, 256, 0, stream>>>(w_up, Wt);
    k_offset_conv<<<128, 256, 0, stream>>>(x, wofft, b_off, om);
    k_prep_coeff<<<1152, 256, 0, stream>>>(om, cidx, cwgt);
    k_deform_gemm<<<2048, 256, 0, stream>>>(x, Wd, cidx, cwgt, g1, be1, mu1, va1, yout);
    k_deconv_gemm<<<4096, 256, 0, stream>>>(yout, Wt, g2, be2, mu2, va2, up);
}

// Round 2
// 1535.086 us; speedup vs baseline: 1.8584x; 1.8584x over previous
//
#include <hip/hip_runtime.h>
#include <cstddef>

// DeformLayer on MI355X. Round 2: bf16 MFMA for deform-conv GEMM and deconv GEMM.
// Structure per kernel: M=256 (all out-channels) x N=64 (one pixel row), K chunks
// of 32 (one 16x16x32 MFMA K-step). Weights pre-tiled into frag-ready [o][40]
// bf16 layout (pad 8 -> 80B row stride, 2-way LDS aliasing = free), staged via
// global_load_lds width=16. B operand (gathered vals / y-taps) computed in regs,
// packed bf16, written to LDS [n][40].

#define B_EPS 1e-5f

typedef __bf16 bf16x8 __attribute__((ext_vector_type(8)));
typedef float f32x4 __attribute__((ext_vector_type(4)));
typedef unsigned short u16;
typedef unsigned int u32;

__device__ __forceinline__ u32 bfr(float f) {          // fp32 -> bf16 bits (RNE)
    u32 u = __float_as_uint(f);
    return (u + 0x7FFFu + ((u >> 16) & 1u)) >> 16;
}

__device__ __forceinline__ void load_lds16(const void* g, void* l) {
    __builtin_amdgcn_global_load_lds(
        (const __attribute__((address_space(1))) unsigned int*)g,
        (__attribute__((address_space(3))) unsigned int*)l, 16, 0, 0);
}

// ---------------- tiny prep kernels ----------------
// w_off[27][256][9] -> wofft[c][co*9+t] (uniform scalar loads in offset conv)
__global__ __launch_bounds__(256) void k_tr_woff(const float* __restrict__ w,
                                                 float* __restrict__ o) {
    int i = blockIdx.x * 256 + threadIdx.x;      // 62208
    int t9 = i % 9; int r = i / 9; int c = r & 255; int co = r >> 8;
    o[c * 243 + co * 9 + t9] = w[i];
}

// w_dcn[o][c][9] -> Wdb[k][cc][o][40] bf16 (frag-ready A tiles, kk=c within chunk)
__global__ __launch_bounds__(256) void k_prep_wdb(const float* __restrict__ w,
                                                  u16* __restrict__ o) {
    int i = blockIdx.x * 256 + threadIdx.x;      // 737280 = 2880*256
    int kk = i % 40; int e = i / 40;
    int oc = e & 255; e >>= 8;
    int cc = e & 7; int k = e >> 3;
    float v = (kk < 32) ? w[oc * 2304 + (cc * 32 + kk) * 9 + k] : 0.f;
    o[i] = (u16)bfr(v);
}

// w_up[ci][co][wr][wc] -> Wtb[cls][cc][o][40] bf16, kk = ci_l*4 + tap
__global__ __launch_bounds__(256) void k_prep_wtb(const float* __restrict__ w,
                                                  u16* __restrict__ o) {
    int i = blockIdx.x * 256 + threadIdx.x;      // 1310720 = 5120*256
    int kk = i % 40; int e = i / 40;
    int oc = e & 255; e >>= 8;
    int cc = e & 31; int cls = e >> 5;
    float v = 0.f;
    if (kk < 32) {
        int ci = cc * 8 + (kk >> 2), tap = kk & 3;
        int ca = cls >> 1, cb = cls & 1;
        int wr = (tap >> 1) ? (ca ? 0 : 1) : (ca ? 2 : 3);
        int wc = (tap & 1) ? (cb ? 0 : 1) : (cb ? 2 : 3);
        v = w[ci * 4096 + oc * 16 + wr * 4 + wc];
    }
    o[i] = (u16)bfr(v);
}

// folded BN params: bnp = [sc1|bi1|sc2|bi2], 4x256 floats
__global__ __launch_bounds__(256) void k_bn_prep(
    const float* g1, const float* be1, const float* mu1, const float* va1,
    const float* g2, const float* be2, const float* mu2, const float* va2,
    float* bnp) {
    int t = threadIdx.x;
    float s1 = g1[t] * rsqrtf(va1[t] + B_EPS);
    bnp[t] = s1; bnp[256 + t] = be1[t] - mu1[t] * s1;
    float s2 = g2[t] * rsqrtf(va2[t] + B_EPS);
    bnp[512 + t] = s2; bnp[768 + t] = be2[t] - mu2[t] * s2;
}

// ---------------- offset conv: om[b][27][64][64] ----------------
__global__ __launch_bounds__(256) void k_offset_conv(
    const float* __restrict__ x, const float* __restrict__ wofft,
    const float* __restrict__ b_off, float* __restrict__ om)
{
    const int t = threadIdx.x;
    const int b = blockIdx.x >> 4;
    const int h = ((blockIdx.x & 15) << 2) + (t >> 6);
    const int w = t & 63;
    const float* xb = x + ((size_t)b << 20);
    float acc[27];
#pragma unroll
    for (int i = 0; i < 27; ++i) acc[i] = b_off[i];
    for (int c = 0; c < 256; ++c) {
        const float* xc = xb + (c << 12);
        float xv[9];
#pragma unroll
        for (int tr = 0; tr < 3; ++tr) {
            int hh = h + tr - 1;
            bool vy = (unsigned)hh < 64u;
#pragma unroll
            for (int tc = 0; tc < 3; ++tc) {
                int ww = w + tc - 1;
                xv[tr * 3 + tc] = (vy && (unsigned)ww < 64u) ? xc[(hh << 6) + ww] : 0.f;
            }
        }
        const float* wc = wofft + c * 243;
#pragma unroll
        for (int co = 0; co < 27; ++co)
#pragma unroll
            for (int k = 0; k < 9; ++k)
                acc[co] = fmaf(xv[k], wc[co * 9 + k], acc[co]);
    }
    float* omb = om + (size_t)b * 110592 + (h << 6) + w;
#pragma unroll
    for (int co = 0; co < 27; ++co) {
        float a = acc[co];
        if (co >= 18) a = 1.f / (1.f + __expf(-a));
        omb[co << 12] = a;
    }
}

// ---------------- bilinear coeff prep (packed: 4x u16 idx + 4x bf16 wgt) ------
__global__ __launch_bounds__(256) void k_prep_coeff(
    const float* __restrict__ om, uint4* __restrict__ cpk)
{
    int i = blockIdx.x * 256 + threadIdx.x;      // 294912
    int pix = i & 4095;
    int bk = i >> 12;
    int k = bk % 9;
    int b = bk / 9;
    int h = pix >> 6, w = pix & 63;
    const float* omb = om + (size_t)b * 110592;
    float dy = omb[(k << 12) + pix];
    float dx = omb[((9 + k) << 12) + pix];
    float m  = omb[((18 + k) << 12) + pix];
    float py = dy + (float)(k / 3 - 1 + h);
    float px = dx + (float)(k % 3 - 1 + w);
    float y0f = floorf(py), x0f = floorf(px);
    float wy = py - y0f, wx = px - x0f;
    int y0 = (int)y0f, x0 = (int)x0f;
    int y1 = y0 + 1, x1 = x0 + 1;
    float vy0 = ((unsigned)y0 < 64u) ? 1.f : 0.f;
    float vy1 = ((unsigned)y1 < 64u) ? 1.f : 0.f;
    float vx0 = ((unsigned)x0 < 64u) ? 1.f : 0.f;
    float vx1 = ((unsigned)x1 < 64u) ? 1.f : 0.f;
    int cy0 = min(max(y0, 0), 63), cy1 = min(max(y1, 0), 63);
    int cx0 = min(max(x0, 0), 63), cx1 = min(max(x1, 0), 63);
    u32 xw = (u32)((cy0 << 6) + cx0) | ((u32)((cy0 << 6) + cx1) << 16);
    u32 yw = (u32)((cy1 << 6) + cx0) | ((u32)((cy1 << 6) + cx1) << 16);
    float w00 = m * (1.f - wy) * (1.f - wx) * vy0 * vx0;
    float w01 = m * (1.f - wy) * wx         * vy0 * vx1;
    float w10 = m * wy         * (1.f - wx) * vy1 * vx0;
    float w11 = m * wy         * wx         * vy1 * vx1;
    u32 zw = bfr(w00) | (bfr(w01) << 16);
    u32 ww2 = bfr(w10) | (bfr(w11) << 16);
    cpk[i] = make_uint4(xw, yw, zw, ww2);
}

// ---------------- deform conv MFMA GEMM + BN1 + ReLU -> y ----------------
// block: batch b, all 256 o, one pixel row (64). K = 9k x 256c, chunks of 32 c.
__global__ __launch_bounds__(256) void k_deform_mfma(
    const float* __restrict__ x, const u16* __restrict__ Wdb,
    const uint4* __restrict__ cpk, const float* __restrict__ bnp,
    float* __restrict__ yout)
{
    __shared__ __align__(16) u16 sA[256 * 40];
    __shared__ __align__(16) u16 sB[64 * 40];
    const int t = threadIdx.x;
    const int row = blockIdx.x & 63;
    const int b = blockIdx.x >> 6;
    const int pix0 = row << 6;
    const int p = t >> 2;        // gather pixel 0..63
    const int g = t & 3;         // c subgroup (8 channels each)
    const float* xb = x + ((size_t)b << 20);

    const int lane = t & 63;
    const int wv = t >> 6;
    const int quad = lane >> 4;
    const int ln = lane & 15;

    f32x4 acc[4][4];
#pragma unroll
    for (int i = 0; i < 4; ++i)
#pragma unroll
        for (int j = 0; j < 4; ++j) acc[i][j] = (f32x4)0.f;

    uint4 q = make_uint4(0, 0, 0, 0);
    for (int ch = 0; ch < 72; ++ch) {
        const int k = ch >> 3;
        const int c0 = (ch & 7) << 5;
        if ((ch & 7) == 0)
            q = cpk[(size_t)(b * 9 + k) * 4096 + pix0 + p];
        const int i00 = q.x & 0xFFFF, i01 = q.x >> 16;
        const int i10 = q.y & 0xFFFF, i11 = q.y >> 16;
        const float w00 = __uint_as_float(q.z << 16);
        const float w01 = __uint_as_float(q.z & 0xFFFF0000u);
        const float w10 = __uint_as_float(q.w << 16);
        const float w11 = __uint_as_float(q.w & 0xFFFF0000u);
        u32 pk[4];
#pragma unroll
        for (int j = 0; j < 8; ++j) {
            const float* xc = xb + ((size_t)(c0 + g * 8 + j) << 12);
            float v = w00 * xc[i00] + w01 * xc[i01] + w10 * xc[i10] + w11 * xc[i11];
            u32 bv = bfr(v);
            if ((j & 1) == 0) pk[j >> 1] = bv; else pk[j >> 1] |= bv << 16;
        }
        __syncthreads();                       // prior frag reads done
        const u16* gA = Wdb + ch * 10240;      // 20480 B tile
#pragma unroll
        for (int i = 0; i < 5; ++i)
            load_lds16(gA + i * 2048 + t * 8, (char*)sA + i * 4096 + t * 16);
        *(uint4*)&sB[p * 40 + g * 8] = *(const uint4*)pk;
        __syncthreads();                       // drains vmcnt incl. lds loads

        bf16x8 af[4], bg[4];
#pragma unroll
        for (int i = 0; i < 4; ++i) {
            af[i] = *(const bf16x8*)&sA[(wv * 64 + i * 16 + ln) * 40 + quad * 8];
            bg[i] = *(const bf16x8*)&sB[(i * 16 + ln) * 40 + quad * 8];
        }
#pragma unroll
        for (int mi = 0; mi < 4; ++mi)
#pragma unroll
            for (int ni = 0; ni < 4; ++ni)
                acc[mi][ni] = __builtin_amdgcn_mfma_f32_16x16x32_bf16(
                    af[mi], bg[ni], acc[mi][ni], 0, 0, 0);
    }
    const float* sc1 = bnp;
    const float* bi1 = bnp + 256;
    float* yb2 = yout + ((size_t)b << 20);
#pragma unroll
    for (int mi = 0; mi < 4; ++mi) {
#pragma unroll
        for (int r = 0; r < 4; ++r) {
            int o = wv * 64 + mi * 16 + quad * 4 + r;
            float sc = sc1[o], bi = bi1[o];
#pragma unroll
            for (int ni = 0; ni < 4; ++ni) {
                float v = fmaxf(fmaf(acc[mi][ni][r], sc, bi), 0.f);
                yb2[((size_t)o << 12) + pix0 + ni * 16 + ln] = v;
            }
        }
    }
}

// ---------------- deconv MFMA GEMM + BN2 + ReLU -> up ----------------
// block: b, parity class (ca,cb), all 256 o, one output row h0 (64 pix).
// K = 256 ci x 4 taps = 1024, chunks of 32 (8 ci).
__global__ __launch_bounds__(256) void k_deconv_mfma(
    const float* __restrict__ y, const u16* __restrict__ Wtb,
    const float* __restrict__ bnp, float* __restrict__ up)
{
    __shared__ __align__(16) u16 sA[256 * 40];
    __shared__ __align__(16) u16 sB[64 * 40];
    const int t = threadIdx.x;
    const int h0 = blockIdx.x & 63;
    const int cls = (blockIdx.x >> 6) & 3;
    const int b = blockIdx.x >> 8;
    const int ca = cls >> 1, cb = cls & 1;
    const int DH0 = ca ? 0 : -1, DH1 = ca ? 1 : 0;
    const int DW0 = cb ? 0 : -1, DW1 = cb ? 1 : 0;
    const float* yb = y + ((size_t)b << 20);
    const int p = t >> 2, g = t & 3;

    const int lane = t & 63;
    const int wv = t >> 6;
    const int quad = lane >> 4;
    const int ln = lane & 15;

    f32x4 acc[4][4];
#pragma unroll
    for (int i = 0; i < 4; ++i)
#pragma unroll
        for (int j = 0; j < 4; ++j) acc[i][j] = (f32x4)0.f;

    for (int cc = 0; cc < 32; ++cc) {
        u32 pk[4];
#pragma unroll
        for (int j = 0; j < 8; ++j) {
            int kk = g * 8 + j;
            int ci = (cc << 3) + (kk >> 2);
            int tap = kk & 3;
            int hh = h0 + ((tap >> 1) ? DH1 : DH0);
            int ww = p + ((tap & 1) ? DW1 : DW0);
            float v = ((unsigned)hh < 64u && (unsigned)ww < 64u)
                      ? yb[((size_t)ci << 12) + (hh << 6) + ww] : 0.f;
            u32 bv = bfr(v);
            if ((j & 1) == 0) pk[j >> 1] = bv; else pk[j >> 1] |= bv << 16;
        }
        __syncthreads();
        const u16* gA = Wtb + (size_t)(cls * 32 + cc) * 10240;
#pragma unroll
        for (int i = 0; i < 5; ++i)
            load_lds16(gA + i * 2048 + t * 8, (char*)sA + i * 4096 + t * 16);
        *(uint4*)&sB[p * 40 + g * 8] = *(const uint4*)pk;
        __syncthreads();

        bf16x8 af[4], bg[4];
#pragma unroll
        for (int i = 0; i < 4; ++i) {
            af[i] = *(const bf16x8*)&sA[(wv * 64 + i * 16 + ln) * 40 + quad * 8];
            bg[i] = *(const bf16x8*)&sB[(i * 16 + ln) * 40 + quad * 8];
        }
#pragma unroll
        for (int mi = 0; mi < 4; ++mi)
#pragma unroll
            for (int ni = 0; ni < 4; ++ni)
                acc[mi][ni] = __builtin_amdgcn_mfma_f32_16x16x32_bf16(
                    af[mi], bg[ni], acc[mi][ni], 0, 0, 0);
    }
    const float* sc2 = bnp + 512;
    const float* bi2 = bnp + 768;
    float* ub = up + ((size_t)b << 22);
    const int pr = (h0 << 1) + ca;
#pragma unroll
    for (int mi = 0; mi < 4; ++mi) {
#pragma unroll
        for (int r = 0; r < 4; ++r) {
            int o = wv * 64 + mi * 16 + quad * 4 + r;
            float sc = sc2[o], bi = bi2[o];
#pragma unroll
            for (int ni = 0; ni < 4; ++ni) {
                int qc = ((ni * 16 + ln) << 1) + cb;
                float v = fmaxf(fmaf(acc[mi][ni][r], sc, bi), 0.f);
                ub[((size_t)o << 14) + (pr << 7) + qc] = v;
            }
        }
    }
}

extern "C" void kernel_launch(void* const* d_in, const int* in_sizes, int n_in,
                              void* d_out, int out_size, void* d_ws, size_t ws_size,
                              hipStream_t stream)
{
    const float* x     = (const float*)d_in[0];
    const float* w_off = (const float*)d_in[1];
    const float* b_off = (const float*)d_in[2];
    const float* w_dcn = (const float*)d_in[3];
    const float* g1    = (const float*)d_in[4];
    const float* be1   = (const float*)d_in[5];
    const float* mu1   = (const float*)d_in[6];
    const float* va1   = (const float*)d_in[7];
    const float* w_up  = (const float*)d_in[8];
    const float* g2    = (const float*)d_in[9];
    const float* be2   = (const float*)d_in[10];
    const float* mu2   = (const float*)d_in[11];
    const float* va2   = (const float*)d_in[12];

    float* yout = (float*)d_out;                 // 8*256*64*64
    float* up   = (float*)d_out + 8388608;       // 8*256*128*128

    char* ws = (char*)d_ws;
    float* om    = (float*)(ws + 0);             // 3,538,944 B
    float* wofft = (float*)(ws + 3538944);       //   248,832 B
    uint4* cpk   = (uint4*)(ws + 3787776);       // 4,718,592 B
    u16*   Wdb   = (u16*)  (ws + 8506368);       // 1,474,560 B
    u16*   Wtb   = (u16*)  (ws + 9980928);       // 2,621,440 B
    float* bnp   = (float*)(ws + 12602368);      //     4,096 B
    // total ws: 12.6 MB

    k_tr_woff   <<<243,  256, 0, stream>>>(w_off, wofft);
    k_prep_wdb  <<<2880, 256, 0, stream>>>(w_dcn, Wdb);
    k_prep_wtb  <<<5120, 256, 0, stream>>>(w_up, Wtb);
    k_bn_prep   <<<1,    256, 0, stream>>>(g1, be1, mu1, va1, g2, be2, mu2, va2, bnp);
    k_offset_conv<<<128, 256, 0, stream>>>(x, wofft, b_off, om);
    k_prep_coeff<<<1152, 256, 0, stream>>>(om, cpk);
    k_deform_mfma<<<512, 256, 0, stream>>>(x, Wdb, cpk, bnp, yout);
    k_deconv_mfma<<<2048,256, 0, stream>>>(yout, Wtb, bnp, up);
}

// Round 3
// 791.391 us; speedup vs baseline: 3.6048x; 1.9397x over previous
//
#include <hip/hip_runtime.h>
#include <cstddef>

// DeformLayer on MI355X. Round 3: fix offset-conv starvation (890us @ 6% occ,
// 3% VALU) by splitting the 256-channel reduction across 8 chunks -> 1024
// blocks + fp32 atomicAdd accumulation into bias-initialized om. Sigmoid of the
// mask moves into k_prep_coeff. Deform/deconv MFMA GEMMs unchanged from R2.

#define B_EPS 1e-5f

typedef __bf16 bf16x8 __attribute__((ext_vector_type(8)));
typedef float f32x4 __attribute__((ext_vector_type(4)));
typedef unsigned short u16;
typedef unsigned int u32;

__device__ __forceinline__ u32 bfr(float f) {          // fp32 -> bf16 bits (RNE)
    u32 u = __float_as_uint(f);
    return (u + 0x7FFFu + ((u >> 16) & 1u)) >> 16;
}

__device__ __forceinline__ void load_lds16(const void* g, void* l) {
    __builtin_amdgcn_global_load_lds(
        (const __attribute__((address_space(1))) unsigned int*)g,
        (__attribute__((address_space(3))) unsigned int*)l, 16, 0, 0);
}

// ---------------- tiny prep kernels ----------------
// w_off[27][256][9] -> wofft[c][co*9+t] (uniform scalar loads in offset conv)
__global__ __launch_bounds__(256) void k_tr_woff(const float* __restrict__ w,
                                                 float* __restrict__ o) {
    int i = blockIdx.x * 256 + threadIdx.x;      // 62208
    int t9 = i % 9; int r = i / 9; int c = r & 255; int co = r >> 8;
    o[c * 243 + co * 9 + t9] = w[i];
}

// w_dcn[o][c][9] -> Wdb[k][cc][o][40] bf16 (frag-ready A tiles, kk=c within chunk)
__global__ __launch_bounds__(256) void k_prep_wdb(const float* __restrict__ w,
                                                  u16* __restrict__ o) {
    int i = blockIdx.x * 256 + threadIdx.x;      // 737280 = 2880*256
    int kk = i % 40; int e = i / 40;
    int oc = e & 255; e >>= 8;
    int cc = e & 7; int k = e >> 3;
    float v = (kk < 32) ? w[oc * 2304 + (cc * 32 + kk) * 9 + k] : 0.f;
    o[i] = (u16)bfr(v);
}

// w_up[ci][co][wr][wc] -> Wtb[cls][cc][o][40] bf16, kk = ci_l*4 + tap
__global__ __launch_bounds__(256) void k_prep_wtb(const float* __restrict__ w,
                                                  u16* __restrict__ o) {
    int i = blockIdx.x * 256 + threadIdx.x;      // 1310720 = 5120*256
    int kk = i % 40; int e = i / 40;
    int oc = e & 255; e >>= 8;
    int cc = e & 31; int cls = e >> 5;
    float v = 0.f;
    if (kk < 32) {
        int ci = cc * 8 + (kk >> 2), tap = kk & 3;
        int ca = cls >> 1, cb = cls & 1;
        int wr = (tap >> 1) ? (ca ? 0 : 1) : (ca ? 2 : 3);
        int wc = (tap & 1) ? (cb ? 0 : 1) : (cb ? 2 : 3);
        v = w[ci * 4096 + oc * 16 + wr * 4 + wc];
    }
    o[i] = (u16)bfr(v);
}

// folded BN params: bnp = [sc1|bi1|sc2|bi2], 4x256 floats
__global__ __launch_bounds__(256) void k_bn_prep(
    const float* g1, const float* be1, const float* mu1, const float* va1,
    const float* g2, const float* be2, const float* mu2, const float* va2,
    float* bnp) {
    int t = threadIdx.x;
    float s1 = g1[t] * rsqrtf(va1[t] + B_EPS);
    bnp[t] = s1; bnp[256 + t] = be1[t] - mu1[t] * s1;
    float s2 = g2[t] * rsqrtf(va2[t] + B_EPS);
    bnp[512 + t] = s2; bnp[768 + t] = be2[t] - mu2[t] * s2;
}

// om init: om[b][27][4096] = b_off[co]  (atomic accumulation base)
__global__ __launch_bounds__(256) void k_om_init(const float* __restrict__ b_off,
                                                 float* __restrict__ om) {
    int i = blockIdx.x * 256 + threadIdx.x;      // 884736 = 3456*256
    int co = (i >> 12) % 27;
    om[i] = b_off[co];
}

// ---------------- offset conv partial: 8 c-chunks, atomicAdd into om ---------
// block: b(8) x rowgrp(16) x chunk(8) = 1024 blocks; thread = one pixel,
// 27 fp32 accumulators over 32 input channels.
__global__ __launch_bounds__(256) void k_offset_conv_part(
    const float* __restrict__ x, const float* __restrict__ wofft,
    float* __restrict__ om)
{
    const int t = threadIdx.x;
    const int chunk = blockIdx.x & 7;
    const int rg = (blockIdx.x >> 3) & 15;
    const int b = blockIdx.x >> 7;
    const int h = (rg << 2) + (t >> 6);
    const int w = t & 63;
    const int c0 = chunk << 5;
    const float* xb = x + ((size_t)b << 20);
    float acc[27];
#pragma unroll
    for (int i = 0; i < 27; ++i) acc[i] = 0.f;
    for (int cl = 0; cl < 32; ++cl) {
        const int c = c0 + cl;
        const float* xc = xb + (c << 12);
        float xv[9];
#pragma unroll
        for (int tr = 0; tr < 3; ++tr) {
            int hh = h + tr - 1;
            bool vy = (unsigned)hh < 64u;
#pragma unroll
            for (int tc = 0; tc < 3; ++tc) {
                int ww = w + tc - 1;
                xv[tr * 3 + tc] = (vy && (unsigned)ww < 64u) ? xc[(hh << 6) + ww] : 0.f;
            }
        }
        const float* wc = wofft + c * 243;
#pragma unroll
        for (int co = 0; co < 27; ++co)
#pragma unroll
            for (int k = 0; k < 9; ++k)
                acc[co] = fmaf(xv[k], wc[co * 9 + k], acc[co]);
    }
    float* omb = om + (size_t)b * 110592 + (h << 6) + w;
#pragma unroll
    for (int co = 0; co < 27; ++co)
        atomicAdd(&omb[co << 12], acc[co]);
}

// ---------------- bilinear coeff prep (packed: 4x u16 idx + 4x bf16 wgt) ------
// mask channel is RAW here (atomic accumulation) -> apply sigmoid now.
__global__ __launch_bounds__(256) void k_prep_coeff(
    const float* __restrict__ om, uint4* __restrict__ cpk)
{
    int i = blockIdx.x * 256 + threadIdx.x;      // 294912
    int pix = i & 4095;
    int bk = i >> 12;
    int k = bk % 9;
    int b = bk / 9;
    int h = pix >> 6, w = pix & 63;
    const float* omb = om + (size_t)b * 110592;
    float dy = omb[(k << 12) + pix];
    float dx = omb[((9 + k) << 12) + pix];
    float mr = omb[((18 + k) << 12) + pix];
    float m  = 1.f / (1.f + __expf(-mr));
    float py = dy + (float)(k / 3 - 1 + h);
    float px = dx + (float)(k % 3 - 1 + w);
    float y0f = floorf(py), x0f = floorf(px);
    float wy = py - y0f, wx = px - x0f;
    int y0 = (int)y0f, x0 = (int)x0f;
    int y1 = y0 + 1, x1 = x0 + 1;
    float vy0 = ((unsigned)y0 < 64u) ? 1.f : 0.f;
    float vy1 = ((unsigned)y1 < 64u) ? 1.f : 0.f;
    float vx0 = ((unsigned)x0 < 64u) ? 1.f : 0.f;
    float vx1 = ((unsigned)x1 < 64u) ? 1.f : 0.f;
    int cy0 = min(max(y0, 0), 63), cy1 = min(max(y1, 0), 63);
    int cx0 = min(max(x0, 0), 63), cx1 = min(max(x1, 0), 63);
    u32 xw = (u32)((cy0 << 6) + cx0) | ((u32)((cy0 << 6) + cx1) << 16);
    u32 yw = (u32)((cy1 << 6) + cx0) | ((u32)((cy1 << 6) + cx1) << 16);
    float w00 = m * (1.f - wy) * (1.f - wx) * vy0 * vx0;
    float w01 = m * (1.f - wy) * wx         * vy0 * vx1;
    float w10 = m * wy         * (1.f - wx) * vy1 * vx0;
    float w11 = m * wy         * wx         * vy1 * vx1;
    u32 zw = bfr(w00) | (bfr(w01) << 16);
    u32 ww2 = bfr(w10) | (bfr(w11) << 16);
    cpk[i] = make_uint4(xw, yw, zw, ww2);
}

// ---------------- deform conv MFMA GEMM + BN1 + ReLU -> y ----------------
// block: batch b, all 256 o, one pixel row (64). K = 9k x 256c, chunks of 32 c.
__global__ __launch_bounds__(256) void k_deform_mfma(
    const float* __restrict__ x, const u16* __restrict__ Wdb,
    const uint4* __restrict__ cpk, const float* __restrict__ bnp,
    float* __restrict__ yout)
{
    __shared__ __align__(16) u16 sA[256 * 40];
    __shared__ __align__(16) u16 sB[64 * 40];
    const int t = threadIdx.x;
    const int row = blockIdx.x & 63;
    const int b = blockIdx.x >> 6;
    const int pix0 = row << 6;
    const int p = t >> 2;        // gather pixel 0..63
    const int g = t & 3;         // c subgroup (8 channels each)
    const float* xb = x + ((size_t)b << 20);

    const int lane = t & 63;
    const int wv = t >> 6;
    const int quad = lane >> 4;
    const int ln = lane & 15;

    f32x4 acc[4][4];
#pragma unroll
    for (int i = 0; i < 4; ++i)
#pragma unroll
        for (int j = 0; j < 4; ++j) acc[i][j] = (f32x4)0.f;

    uint4 q = make_uint4(0, 0, 0, 0);
    for (int ch = 0; ch < 72; ++ch) {
        const int k = ch >> 3;
        const int c0 = (ch & 7) << 5;
        if ((ch & 7) == 0)
            q = cpk[(size_t)(b * 9 + k) * 4096 + pix0 + p];
        const int i00 = q.x & 0xFFFF, i01 = q.x >> 16;
        const int i10 = q.y & 0xFFFF, i11 = q.y >> 16;
        const float w00 = __uint_as_float(q.z << 16);
        const float w01 = __uint_as_float(q.z & 0xFFFF0000u);
        const float w10 = __uint_as_float(q.w << 16);
        const float w11 = __uint_as_float(q.w & 0xFFFF0000u);
        u32 pk[4];
#pragma unroll
        for (int j = 0; j < 8; ++j) {
            const float* xc = xb + ((size_t)(c0 + g * 8 + j) << 12);
            float v = w00 * xc[i00] + w01 * xc[i01] + w10 * xc[i10] + w11 * xc[i11];
            u32 bv = bfr(v);
            if ((j & 1) == 0) pk[j >> 1] = bv; else pk[j >> 1] |= bv << 16;
        }
        __syncthreads();                       // prior frag reads done
        const u16* gA = Wdb + ch * 10240;      // 20480 B tile
#pragma unroll
        for (int i = 0; i < 5; ++i)
            load_lds16(gA + i * 2048 + t * 8, (char*)sA + i * 4096 + t * 16);
        *(uint4*)&sB[p * 40 + g * 8] = *(const uint4*)pk;
        __syncthreads();                       // drains vmcnt incl. lds loads

        bf16x8 af[4], bg[4];
#pragma unroll
        for (int i = 0; i < 4; ++i) {
            af[i] = *(const bf16x8*)&sA[(wv * 64 + i * 16 + ln) * 40 + quad * 8];
            bg[i] = *(const bf16x8*)&sB[(i * 16 + ln) * 40 + quad * 8];
        }
#pragma unroll
        for (int mi = 0; mi < 4; ++mi)
#pragma unroll
            for (int ni = 0; ni < 4; ++ni)
                acc[mi][ni] = __builtin_amdgcn_mfma_f32_16x16x32_bf16(
                    af[mi], bg[ni], acc[mi][ni], 0, 0, 0);
    }
    const float* sc1 = bnp;
    const float* bi1 = bnp + 256;
    float* yb2 = yout + ((size_t)b << 20);
#pragma unroll
    for (int mi = 0; mi < 4; ++mi) {
#pragma unroll
        for (int r = 0; r < 4; ++r) {
            int o = wv * 64 + mi * 16 + quad * 4 + r;
            float sc = sc1[o], bi = bi1[o];
#pragma unroll
            for (int ni = 0; ni < 4; ++ni) {
                float v = fmaxf(fmaf(acc[mi][ni][r], sc, bi), 0.f);
                yb2[((size_t)o << 12) + pix0 + ni * 16 + ln] = v;
            }
        }
    }
}

// ---------------- deconv MFMA GEMM + BN2 + ReLU -> up ----------------
// block: b, parity class (ca,cb), all 256 o, one output row h0 (64 pix).
// K = 256 ci x 4 taps = 1024, chunks of 32 (8 ci).
__global__ __launch_bounds__(256) void k_deconv_mfma(
    const float* __restrict__ y, const u16* __restrict__ Wtb,
    const float* __restrict__ bnp, float* __restrict__ up)
{
    __shared__ __align__(16) u16 sA[256 * 40];
    __shared__ __align__(16) u16 sB[64 * 40];
    const int t = threadIdx.x;
    const int h0 = blockIdx.x & 63;
    const int cls = (blockIdx.x >> 6) & 3;
    const int b = blockIdx.x >> 8;
    const int ca = cls >> 1, cb = cls & 1;
    const int DH0 = ca ? 0 : -1, DH1 = ca ? 1 : 0;
    const int DW0 = cb ? 0 : -1, DW1 = cb ? 1 : 0;
    const float* yb = y + ((size_t)b << 20);
    const int p = t >> 2, g = t & 3;

    const int lane = t & 63;
    const int wv = t >> 6;
    const int quad = lane >> 4;
    const int ln = lane & 15;

    f32x4 acc[4][4];
#pragma unroll
    for (int i = 0; i < 4; ++i)
#pragma unroll
        for (int j = 0; j < 4; ++j) acc[i][j] = (f32x4)0.f;

    for (int cc = 0; cc < 32; ++cc) {
        u32 pk[4];
#pragma unroll
        for (int j = 0; j < 8; ++j) {
            int kk = g * 8 + j;
            int ci = (cc << 3) + (kk >> 2);
            int tap = kk & 3;
            int hh = h0 + ((tap >> 1) ? DH1 : DH0);
            int ww = p + ((tap & 1) ? DW1 : DW0);
            float v = ((unsigned)hh < 64u && (unsigned)ww < 64u)
                      ? yb[((size_t)ci << 12) + (hh << 6) + ww] : 0.f;
            u32 bv = bfr(v);
            if ((j & 1) == 0) pk[j >> 1] = bv; else pk[j >> 1] |= bv << 16;
        }
        __syncthreads();
        const u16* gA = Wtb + (size_t)(cls * 32 + cc) * 10240;
#pragma unroll
        for (int i = 0; i < 5; ++i)
            load_lds16(gA + i * 2048 + t * 8, (char*)sA + i * 4096 + t * 16);
        *(uint4*)&sB[p * 40 + g * 8] = *(const uint4*)pk;
        __syncthreads();

        bf16x8 af[4], bg[4];
#pragma unroll
        for (int i = 0; i < 4; ++i) {
            af[i] = *(const bf16x8*)&sA[(wv * 64 + i * 16 + ln) * 40 + quad * 8];
            bg[i] = *(const bf16x8*)&sB[(i * 16 + ln) * 40 + quad * 8];
        }
#pragma unroll
        for (int mi = 0; mi < 4; ++mi)
#pragma unroll
            for (int ni = 0; ni < 4; ++ni)
                acc[mi][ni] = __builtin_amdgcn_mfma_f32_16x16x32_bf16(
                    af[mi], bg[ni], acc[mi][ni], 0, 0, 0);
    }
    const float* sc2 = bnp + 512;
    const float* bi2 = bnp + 768;
    float* ub = up + ((size_t)b << 22);
    const int pr = (h0 << 1) + ca;
#pragma unroll
    for (int mi = 0; mi < 4; ++mi) {
#pragma unroll
        for (int r = 0; r < 4; ++r) {
            int o = wv * 64 + mi * 16 + quad * 4 + r;
            float sc = sc2[o], bi = bi2[o];
#pragma unroll
            for (int ni = 0; ni < 4; ++ni) {
                int qc = ((ni * 16 + ln) << 1) + cb;
                float v = fmaxf(fmaf(acc[mi][ni][r], sc, bi), 0.f);
                ub[((size_t)o << 14) + (pr << 7) + qc] = v;
            }
        }
    }
}

extern "C" void kernel_launch(void* const* d_in, const int* in_sizes, int n_in,
                              void* d_out, int out_size, void* d_ws, size_t ws_size,
                              hipStream_t stream)
{
    const float* x     = (const float*)d_in[0];
    const float* w_off = (const float*)d_in[1];
    const float* b_off = (const float*)d_in[2];
    const float* w_dcn = (const float*)d_in[3];
    const float* g1    = (const float*)d_in[4];
    const float* be1   = (const float*)d_in[5];
    const float* mu1   = (const float*)d_in[6];
    const float* va1   = (const float*)d_in[7];
    const float* w_up  = (const float*)d_in[8];
    const float* g2    = (const float*)d_in[9];
    const float* be2   = (const float*)d_in[10];
    const float* mu2   = (const float*)d_in[11];
    const float* va2   = (const float*)d_in[12];

    float* yout = (float*)d_out;                 // 8*256*64*64
    float* up   = (float*)d_out + 8388608;       // 8*256*128*128

    char* ws = (char*)d_ws;
    float* om    = (float*)(ws + 0);             // 3,538,944 B
    float* wofft = (float*)(ws + 3538944);       //   248,832 B
    uint4* cpk   = (uint4*)(ws + 3787776);       // 4,718,592 B
    u16*   Wdb   = (u16*)  (ws + 8506368);       // 1,474,560 B
    u16*   Wtb   = (u16*)  (ws + 9980928);       // 2,621,440 B
    float* bnp   = (float*)(ws + 12602368);      //     4,096 B
    // total ws: 12.6 MB

    k_tr_woff   <<<243,  256, 0, stream>>>(w_off, wofft);
    k_prep_wdb  <<<2880, 256, 0, stream>>>(w_dcn, Wdb);
    k_prep_wtb  <<<5120, 256, 0, stream>>>(w_up, Wtb);
    k_bn_prep   <<<1,    256, 0, stream>>>(g1, be1, mu1, va1, g2, be2, mu2, va2, bnp);
    k_om_init   <<<3456, 256, 0, stream>>>(b_off, om);
    k_offset_conv_part<<<1024, 256, 0, stream>>>(x, wofft, om);
    k_prep_coeff<<<1152, 256, 0, stream>>>(om, cpk);
    k_deform_mfma<<<512, 256, 0, stream>>>(x, Wdb, cpk, bnp, yout);
    k_deconv_mfma<<<2048,256, 0, stream>>>(yout, Wtb, bnp, up);
}